// Round 1
// baseline (410.099 us; speedup 1.0000x reference)
//
#include <hip/hip_runtime.h>

typedef __bf16 bf16;
typedef __bf16 bf16x8 __attribute__((ext_vector_type(8)));
typedef float floatx4 __attribute__((ext_vector_type(4)));

#define BATCH 128
#define SEQ   2048
#define HID   128
#define TWOH  256
#define CH    128
#define NCH   (SEQ / CH)       // 16
#define MTOT  (BATCH * SEQ)    // 262144

__device__ __forceinline__ float fast_tanh(float x) {
    // tanh(x) = 1 - 2/(exp2(2*log2e*x)+1); saturates correctly at +/-inf
    float e = __builtin_amdgcn_exp2f(2.88539008177793f * x);
    return 1.0f - 2.0f * __builtin_amdgcn_rcpf(e + 1.0f);
}
__device__ __forceinline__ float fast_sigmoid(float x) {
    return __builtin_amdgcn_rcpf(1.0f + __builtin_amdgcn_exp2f(-1.44269504088896f * x));
}

// C[m,n] = tanh( sum_k A[m,k] * W[n,k] ), A:[MTOT,128] (f32 or bf16), W:[256,128] f32,
// G out bf16 [MTOT,256]. Block: 128 rows, 2 column passes of 128. 256 thr = 2x2 waves.
template <bool AF32>
__global__ __launch_bounds__(256, 2) void gemm_tanh_k(const void* __restrict__ Aptr,
                                                      const float* __restrict__ W,
                                                      bf16* __restrict__ G) {
    extern __shared__ char smem[];
    bf16* As = (bf16*)smem;          // [128][128], 8-elem groups XOR-swizzled by row&7
    bf16* Bs = As + 128 * 128;

    const int tid  = threadIdx.x;
    const int lane = tid & 63;
    const int wid  = tid >> 6;
    const int wr   = wid >> 1;
    const int wc   = wid & 1;
    const long rowBase = (long)blockIdx.x * 128;

    if (AF32) {
        const float4* A4 = (const float4*)((const float*)Aptr + rowBase * HID);
        #pragma unroll
        for (int it = 0; it < 16; ++it) {
            int i  = it * 256 + tid;   // 0..4095
            int r  = i >> 5;
            int c4 = i & 31;
            float4 v = A4[i];
            int g = c4 >> 1, hf = c4 & 1;
            union { bf16 h[4]; unsigned long long u; } pk;
            pk.h[0] = (bf16)v.x; pk.h[1] = (bf16)v.y;
            pk.h[2] = (bf16)v.z; pk.h[3] = (bf16)v.w;
            *(unsigned long long*)&As[r * 128 + ((g ^ (r & 7)) << 3) + (hf << 2)] = pk.u;
        }
    } else {
        const uint4* A8 = (const uint4*)((const bf16*)Aptr + rowBase * HID);
        #pragma unroll
        for (int it = 0; it < 8; ++it) {
            int i = it * 256 + tid;    // 0..2047
            int r = i >> 4;
            int g = i & 15;
            uint4 v = A8[i];
            *(uint4*)&As[r * 128 + ((g ^ (r & 7)) << 3)] = v;
        }
    }

    const int quad = lane >> 4;
    const int l16  = lane & 15;

    for (int half = 0; half < 2; ++half) {
        if (half) __syncthreads();   // protect Bs from overwrite while pass 0 computes
        const float4* W4 = (const float4*)(W + half * 128 * HID);
        #pragma unroll
        for (int it = 0; it < 16; ++it) {
            int i  = it * 256 + tid;
            int r  = i >> 5;
            int c4 = i & 31;
            float4 v = W4[i];
            int g = c4 >> 1, hf = c4 & 1;
            union { bf16 h[4]; unsigned long long u; } pk;
            pk.h[0] = (bf16)v.x; pk.h[1] = (bf16)v.y;
            pk.h[2] = (bf16)v.z; pk.h[3] = (bf16)v.w;
            *(unsigned long long*)&Bs[r * 128 + ((g ^ (r & 7)) << 3) + (hf << 2)] = pk.u;
        }
        __syncthreads();

        floatx4 acc[4][4];
        #pragma unroll
        for (int a = 0; a < 4; ++a)
            #pragma unroll
            for (int b2 = 0; b2 < 4; ++b2) acc[a][b2] = (floatx4){0.f, 0.f, 0.f, 0.f};

        #pragma unroll
        for (int kk = 0; kk < 128; kk += 32) {
            bf16x8 af[4], bfr[4];
            int kg = (kk >> 3) + quad;
            #pragma unroll
            for (int mi = 0; mi < 4; ++mi) {
                int r = wr * 64 + mi * 16 + l16;
                af[mi] = *(const bf16x8*)&As[r * 128 + ((kg ^ (r & 7)) << 3)];
            }
            #pragma unroll
            for (int ni = 0; ni < 4; ++ni) {
                int n = wc * 64 + ni * 16 + l16;
                bfr[ni] = *(const bf16x8*)&Bs[n * 128 + ((kg ^ (n & 7)) << 3)];
            }
            #pragma unroll
            for (int mi = 0; mi < 4; ++mi)
                #pragma unroll
                for (int ni = 0; ni < 4; ++ni)
                    acc[mi][ni] = __builtin_amdgcn_mfma_f32_16x16x32_bf16(
                        af[mi], bfr[ni], acc[mi][ni], 0, 0, 0);
        }

        // epilogue: tanh -> bf16 -> G.  C/D layout: col=lane&15, row=quad*4+reg
        #pragma unroll
        for (int mi = 0; mi < 4; ++mi) {
            #pragma unroll
            for (int ni = 0; ni < 4; ++ni) {
                int row_l = wr * 64 + mi * 16 + quad * 4;
                int col   = half * 128 + wc * 64 + ni * 16 + l16;
                long gb = (rowBase + row_l) * TWOH + col;
                #pragma unroll
                for (int rr = 0; rr < 4; ++rr)
                    G[gb + (long)rr * TWOH] = (bf16)fast_tanh(acc[mi][ni][rr]);
            }
        }
    }
}

// per-(b,chunk) channel sums of tanh values: P[b*NCH+c][ch] = sum_t G[...]
__global__ __launch_bounds__(256) void chunk_sums_k(const bf16* __restrict__ G,
                                                    float* __restrict__ P) {
    int ch = threadIdx.x;
    long base = (long)blockIdx.x * CH * TWOH + ch;
    float s = 0.f;
    #pragma unroll 8
    for (int t = 0; t < CH; ++t) s += (float)G[base + (long)t * TWOH];
    P[((long)blockIdx.x << 8) + ch] = s;
}

// in-place exclusive scan over the NCH chunks, per (b, ch)
__global__ __launch_bounds__(256) void scan_partials_k(float* __restrict__ P) {
    int ch = threadIdx.x;
    long b = blockIdx.x;
    float run = 0.f;
    for (int c = 0; c < NCH; ++c) {
        long idx = ((b * NCH + c) << 8) + ch;
        float v = P[idx];
        P[idx] = run;
        run += v;
    }
}

// h(t,j) = P2 - relu(P1)*G2 with inclusive prefixes; writes bf16 [MTOT,128]
__global__ __launch_bounds__(128) void compute_h_k(const bf16* __restrict__ G,
                                                   const float* __restrict__ P,
                                                   bf16* __restrict__ Hb) {
    int j = threadIdx.x;
    long blk = blockIdx.x;
    float P1 = P[(blk << 8) + j];
    float P2 = P[(blk << 8) + 128 + j];
    long gbase = blk * CH * TWOH;
    long hbase = blk * CH * HID;
    #pragma unroll 4
    for (int t = 0; t < CH; ++t) {
        float g1 = (float)G[gbase + (long)t * TWOH + j];
        float g2 = (float)G[gbase + (long)t * TWOH + 128 + j];
        P1 += g1;
        P2 += g2;
        float h = P2 - fmaxf(P1, 0.f) * g2;
        Hb[hbase + (long)t * HID + j] = (bf16)h;
    }
}

// layer-1 scan + z = h @ Wfc[1].T + double sigmoid + masked sq-err + reduce
__global__ __launch_bounds__(128) void final_loss_k(const bf16* __restrict__ G,
                                                    const float* __restrict__ P,
                                                    const float* __restrict__ Wfc,
                                                    const int* __restrict__ xlen,
                                                    const float* __restrict__ xlab,
                                                    float* __restrict__ out) {
    __shared__ float hbuf[64][129];
    __shared__ float w0s[128], w1s[128];
    __shared__ float red[2];
    int tid = threadIdx.x;
    int b = blockIdx.x >> 4;
    int c = blockIdx.x & 15;
    w0s[tid] = Wfc[2 * HID + tid];  // layer 1, out 0
    w1s[tid] = Wfc[3 * HID + tid];  // layer 1, out 1
    float P1 = P[((long)blockIdx.x << 8) + tid];
    float P2 = P[((long)blockIdx.x << 8) + 128 + tid];
    long gbase = (long)blockIdx.x * CH * TWOH;
    int xl = xlen[b];
    float lab = xlab[b];
    float lsum = 0.f;
    for (int sub = 0; sub < 2; ++sub) {
        #pragma unroll 4
        for (int t = 0; t < 64; ++t) {
            int tt = sub * 64 + t;
            float g1 = (float)G[gbase + (long)tt * TWOH + tid];
            float g2 = (float)G[gbase + (long)tt * TWOH + 128 + tid];
            P1 += g1;
            P2 += g2;
            hbuf[t][tid] = P2 - fmaxf(P1, 0.f) * g2;
        }
        __syncthreads();
        if (tid < 64) {
            float z0 = 0.f, z1 = 0.f;
            #pragma unroll 8
            for (int j = 0; j < 128; ++j) {
                float hv = hbuf[tid][j];
                z0 += hv * w0s[j];
                z1 += hv * w1s[j];
            }
            float o1 = fast_sigmoid(z1 - z0);  // softmax[:,1] for O=2
            float sg = fast_sigmoid(o1);
            int tg = c * CH + sub * 64 + tid;
            float d = lab - sg;
            if (tg < xl) lsum += d * d;
        }
        __syncthreads();
    }
    #pragma unroll
    for (int off = 32; off; off >>= 1) lsum += __shfl_down(lsum, off);
    if ((tid & 63) == 0) red[tid >> 6] = lsum;
    __syncthreads();
    if (tid == 0) atomicAdd(out, red[0] + red[1]);
}

extern "C" void kernel_launch(void* const* d_in, const int* in_sizes, int n_in,
                              void* d_out, int out_size, void* d_ws, size_t ws_size,
                              hipStream_t stream) {
    const float* x    = (const float*)d_in[0];
    const int*   xlen = (const int*)d_in[1];
    const float* xlab = (const float*)d_in[2];
    const float* Wx2h = (const float*)d_in[3];  // [2,256,128]
    const float* Wfc  = (const float*)d_in[4];  // [2,2,128]
    float* out = (float*)d_out;

    char* ws = (char*)d_ws;
    bf16* G  = (bf16*)ws;                                               // 128 MiB
    bf16* Hb = (bf16*)(ws + (size_t)MTOT * TWOH * sizeof(bf16));        // 64 MiB
    float* P = (float*)(ws + (size_t)MTOT * TWOH * sizeof(bf16) +
                        (size_t)MTOT * HID * sizeof(bf16));             // 2 MiB

    hipMemsetAsync(d_out, 0, sizeof(float), stream);

    dim3 gemmGrid(MTOT / 128);
    size_t smem = 2 * 128 * 128 * sizeof(bf16);

    // layer 0
    gemm_tanh_k<true><<<gemmGrid, 256, smem, stream>>>(x, Wx2h, G);
    chunk_sums_k<<<BATCH * NCH, 256, 0, stream>>>(G, P);
    scan_partials_k<<<BATCH, 256, 0, stream>>>(P);
    compute_h_k<<<BATCH * NCH, 128, 0, stream>>>(G, P, Hb);
    // layer 1 (reuse G and P)
    gemm_tanh_k<false><<<gemmGrid, 256, smem, stream>>>(Hb, Wx2h + TWOH * HID, G);
    chunk_sums_k<<<BATCH * NCH, 256, 0, stream>>>(G, P);
    scan_partials_k<<<BATCH, 256, 0, stream>>>(P);
    final_loss_k<<<BATCH * NCH, 128, 0, stream>>>(G, P, Wfc, xlen, xlab, out);
}